// Round 26
// baseline (85.960 us; speedup 1.0000x reference)
//
#include <hip/hip_runtime.h>

#define D 128
#define NBH 256           // edge-pass blocks; hist and scatter MUST use identical chunking
#define CAP 4096          // max edges per bucket staged in LDS (safe fallback beyond)

typedef __attribute__((ext_vector_type(8))) short bf16x8;
typedef __attribute__((ext_vector_type(4))) float f32x4;
typedef __attribute__((ext_vector_type(8))) unsigned short us8;
typedef __attribute__((ext_vector_type(4))) int i32x4;

static __device__ __forceinline__ float bf2f(unsigned short u) {
    union { unsigned int i; float f; } c; c.i = ((unsigned int)u) << 16; return c.f;
}
static __device__ __forceinline__ unsigned short f2bf(float f) {
    union { float f; unsigned int i; } c; c.f = f;
    unsigned int r = c.i + 0x7FFFu + ((c.i >> 16) & 1u);   // RTN-even
    return (unsigned short)(r >> 16);
}

// ---------------------------------------------------------------------------
// Wt[c][k] = bf16(W[k][c])  (one-time 32 KB transpose+convert; L2-resident)
__global__ __launch_bounds__(256) void k_wprep(const float* __restrict__ W,
                                               unsigned short* __restrict__ Wt) {
    int t = (int)blockIdx.x * 256 + (int)threadIdx.x;
    int k = t >> 7, c = t & 127;
    Wt[c * D + k] = f2bf(W[t]);
}

// ---------------------------------------------------------------------------
// Fused (R18-proven pairing): blocks [0, NBH) = bucket histogram (LDS bins ->
// bucket-major counts2d, zero global atomics) — hides under the GEMM;
// blocks [NBH, ...) = MFMA GEMM hs = bf16(x@W) (unscaled).
__global__ __launch_bounds__(256) void k_gemm_hist(const float* __restrict__ x,
                                                   const unsigned short* __restrict__ Wt,
                                                   const int* __restrict__ dst,
                                                   int* __restrict__ counts2d,
                                                   unsigned short* __restrict__ hs,
                                                   int N, int E, int nbuck) {
    if ((int)blockIdx.x < NBH) {
        __shared__ int bins[1024];                 // nbuck <= 1024
        for (int t = threadIdx.x; t < nbuck; t += 256) bins[t] = 0;
        __syncthreads();
        const int k = (int)blockIdx.x;
        const long long stride = (long long)NBH * 1024;   // NBH*256*4
        for (long long i = ((long long)k * 256 + threadIdx.x) * 4; i < E; i += stride) {
            if (i + 4 <= E) {
                i32x4 d = *(const i32x4*)(dst + i);
                atomicAdd(&bins[d.x >> 6], 1);
                atomicAdd(&bins[d.y >> 6], 1);
                atomicAdd(&bins[d.z >> 6], 1);
                atomicAdd(&bins[d.w >> 6], 1);
            } else {
                for (long long j = i; j < E; ++j) atomicAdd(&bins[dst[j] >> 6], 1);
            }
        }
        __syncthreads();
        for (int t = threadIdx.x; t < nbuck; t += 256)
            counts2d[t * NBH + k] = bins[t];       // bucket-major
        return;
    }

    // ---- GEMM role: 64 rows per block, 16 per wave (proven body) ----
    const int wave = threadIdx.x >> 6;
    const int l    = threadIdx.x & 63;
    const int m0   = ((int)blockIdx.x - NBH) * 64 + wave * 16;
    const int lr   = l & 15;
    const int kg   = l >> 4;
    const int row_a = m0 + lr;

    f32x4 acc[8];
#pragma unroll
    for (int t = 0; t < 8; ++t) acc[t] = (f32x4){0.f, 0.f, 0.f, 0.f};

#pragma unroll
    for (int kk = 0; kk < 4; ++kk) {
        const int kbase = kk * 32 + kg * 8;
        bf16x8 afrag;
        if (row_a < N) {
            const float* xp = x + (size_t)row_a * D + kbase;
            f32x4 x0 = *(const f32x4*)xp;
            f32x4 x1 = *(const f32x4*)(xp + 4);
#pragma unroll
            for (int j = 0; j < 4; ++j) afrag[j] = (short)f2bf(x0[j]);
#pragma unroll
            for (int j = 0; j < 4; ++j) afrag[4 + j] = (short)f2bf(x1[j]);
        } else {
#pragma unroll
            for (int j = 0; j < 8; ++j) afrag[j] = 0;
        }
#pragma unroll
        for (int nt = 0; nt < 8; ++nt) {
            bf16x8 bfrag = *(const bf16x8*)(Wt + (size_t)(nt * 16 + lr) * D + kbase);
            acc[nt] = __builtin_amdgcn_mfma_f32_16x16x32_bf16(afrag, bfrag, acc[nt], 0, 0, 0);
        }
    }

    // D-frag: col = lane&15, row = 4*(lane>>4)+j  (m89-verified)
#pragma unroll
    for (int j = 0; j < 4; ++j) {
        int row = m0 + kg * 4 + j;
        if (row < N) {
#pragma unroll
            for (int nt = 0; nt < 8; ++nt)
                hs[(size_t)row * D + nt * 16 + lr] = f2bf(acc[nt][j]);
        }
    }
}

// ---------------------------------------------------------------------------
// Per-bucket column scan: block b coalesced-loads its 256 per-block counts,
// LDS-scans them, writes back exclusive prefixes (colpre), emits btot[b].
__global__ __launch_bounds__(256) void k_colscan(int* __restrict__ counts2d,
                                                 int* __restrict__ btot) {
    __shared__ int ts[256];
    const int b = (int)blockIdx.x;
    const int t = (int)threadIdx.x;
    int c = counts2d[b * NBH + t];
    ts[t] = c;
    __syncthreads();
    for (int off = 1; off < 256; off <<= 1) {
        int v = (t >= off) ? ts[t - off] : 0;
        __syncthreads();
        ts[t] += v;
        __syncthreads();
    }
    counts2d[b * NBH + t] = ts[t] - c;             // exclusive colpre
    if (t == 255) btot[b] = ts[255];
}

// ---------------------------------------------------------------------------
// Deterministic scatter + inline bucket-offset scan (btscan folded in):
// every block independently computes the exclusive prefix of btot[0..nbuck)
// in LDS, publishes the identical offsets[] values (duplicate-store-safe),
// then scatters its edge subset: position = pref[b] + colpre[b][k] + cursor.
// Zero global atomics. Packed entry: src(16b) | (dst&63)<<16.  N <= 65536.
__global__ __launch_bounds__(256) void k_scatter(const int* __restrict__ src,
                                                 const int* __restrict__ dst,
                                                 const int* __restrict__ btot,
                                                 const int* __restrict__ counts2d,
                                                 int* __restrict__ offsets,
                                                 unsigned int* __restrict__ sorted,
                                                 int E, int nbuck) {
    __shared__ int pref[1025];     // exclusive prefix of btot; pref[nbuck] = total
    __shared__ int ts[256];
    __shared__ int base_l[1024];
    __shared__ int cur[1024];

    // ---- inline exclusive scan of btot (all 256 threads, 4 elems each) ----
    {
        const int t = (int)threadIdx.x;
        int e[4];
        int s = 0;
#pragma unroll
        for (int j = 0; j < 4; ++j) {
            int idx = t * 4 + j;
            int v = (idx < nbuck) ? btot[idx] : 0;
            e[j] = s;
            s += v;
        }
        ts[t] = s;
        __syncthreads();
        for (int off = 1; off < 256; off <<= 1) {
            int v = (t >= off) ? ts[t - off] : 0;
            __syncthreads();
            ts[t] += v;
            __syncthreads();
        }
        int base = ts[t] - s;
#pragma unroll
        for (int j = 0; j < 4; ++j) {
            int idx = t * 4 + j;
            pref[idx] = base + e[j];
        }
        if (t == 255) pref[1024] = ts[255];
        __syncthreads();
        // publish offsets[0..nbuck] (identical values from every block)
        for (int idx = t; idx <= nbuck; idx += 256)
            offsets[idx] = pref[idx];
    }

    const int k = (int)blockIdx.x;
    for (int t = threadIdx.x; t < nbuck; t += 256) {
        base_l[t] = pref[t] + counts2d[t * NBH + k];
        cur[t] = 0;
    }
    __syncthreads();

    const long long stride = (long long)NBH * 1024;
    for (long long i = ((long long)k * 256 + threadIdx.x) * 4; i < E; i += stride) {
        if (i + 4 <= E) {
            i32x4 d = *(const i32x4*)(dst + i);
            i32x4 s = *(const i32x4*)(src + i);
            int p;
            p = base_l[d.x >> 6] + atomicAdd(&cur[d.x >> 6], 1);
            sorted[p] = (unsigned int)(s.x & 0xFFFF) | ((unsigned int)(d.x & 63) << 16);
            p = base_l[d.y >> 6] + atomicAdd(&cur[d.y >> 6], 1);
            sorted[p] = (unsigned int)(s.y & 0xFFFF) | ((unsigned int)(d.y & 63) << 16);
            p = base_l[d.z >> 6] + atomicAdd(&cur[d.z >> 6], 1);
            sorted[p] = (unsigned int)(s.z & 0xFFFF) | ((unsigned int)(d.z & 63) << 16);
            p = base_l[d.w >> 6] + atomicAdd(&cur[d.w >> 6], 1);
            sorted[p] = (unsigned int)(s.w & 0xFFFF) | ((unsigned int)(d.w & 63) << 16);
        } else {
            for (long long j = i; j < E; ++j) {
                int dd = dst[j], ss = src[j];
                int p = base_l[dd >> 6] + atomicAdd(&cur[dd >> 6], 1);
                sorted[p] = (unsigned int)(ss & 0xFFFF) | ((unsigned int)(dd & 63) << 16);
            }
        }
    }
}

// ---------------------------------------------------------------------------
// Per-bucket node degrees -> dinv (reads the bucket's packed edges once).
__global__ __launch_bounds__(256) void k_dinv(const unsigned int* __restrict__ sorted,
                                              const int* __restrict__ offsets,
                                              float* __restrict__ dinv, int N) {
    __shared__ int bins[64];
    const int b = (int)blockIdx.x;
    if (threadIdx.x < 64) bins[threadIdx.x] = 0;
    __syncthreads();
    const int off = offsets[b];
    const int cnt = offsets[b + 1] - off;
    for (int i = threadIdx.x; i < cnt; i += 256)
        atomicAdd(&bins[(sorted[off + i] >> 16) & 63], 1);
    __syncthreads();
    if (threadIdx.x < 64) {
        int v = b * 64 + (int)threadIdx.x;
        if (v < N) dinv[v] = rsqrtf((float)(bins[threadIdx.x] + 1));
    }
}

// ---------------------------------------------------------------------------
// Bucket aggregate, WAVE-PER-NODE edge parallelism: 512 threads = 8 waves;
// all 4 16-lane groups of a wave process the SAME node (edges round-robin by
// group, 2-unrolled -> 8 independent 16B gather streams per wave, zero
// lockstep divergence waste), then cross-group __shfl_xor(16/32) reduction
// (full wave active). Group 0 holds the self-loop term and writes the output.
//   acc = h[v]*dinv[v] + sum h[src]*dinv[src];  out[v] = relu(acc*dinv[v]+b)
__global__ __launch_bounds__(512) void k_aggregate(const unsigned short* __restrict__ hs,
                                                   const unsigned int* __restrict__ sorted,
                                                   const int* __restrict__ offsets,
                                                   const float* __restrict__ dinv,
                                                   const float* __restrict__ bias,
                                                   float* __restrict__ out, int N) {
    __shared__ unsigned short srt[CAP];
    __shared__ int bins[64];
    __shared__ int boff[64];
    __shared__ int cur[64];

    const int bb  = (int)blockIdx.x;
    const int off = offsets[bb];
    const int cnt = offsets[bb + 1] - off;
    const bool fits = (cnt <= CAP);

    if (fits) {
        if (threadIdx.x < 64) bins[threadIdx.x] = 0;
        __syncthreads();
        for (int i = threadIdx.x; i < cnt; i += 512)
            atomicAdd(&bins[(sorted[off + i] >> 16) & 63], 1);
        __syncthreads();
        if (threadIdx.x < 64) {              // full wave 0 active: shfl safe
            const int lane = (int)threadIdx.x;
            int bv = bins[lane];
            int inc = bv;
            for (int o = 1; o < 64; o <<= 1) {
                int t = __shfl_up(inc, o, 64);
                if (lane >= o) inc += t;
            }
            boff[lane] = inc - bv;
            cur[lane] = 0;
        }
        __syncthreads();
        for (int i = threadIdx.x; i < cnt; i += 512) {
            unsigned int e = sorted[off + i];
            int dl = (int)((e >> 16) & 63u);
            int p = boff[dl] + atomicAdd(&cur[dl], 1);
            srt[p] = (unsigned short)(e & 0xFFFFu);
        }
        __syncthreads();
    }

    const int wv   = (int)(threadIdx.x >> 6);   // wave 0..7
    const int lane = (int)(threadIdx.x & 63);
    const int g    = lane >> 4;                 // group 0..3 within wave
    const int sl   = lane & 15;                 // sublane: feature chunk
    const f32x4 b0 = *(const f32x4*)(bias + sl * 8);
    const f32x4 b1 = *(const f32x4*)(bias + sl * 8 + 4);

    for (int t = 0; t < 8; ++t) {
        const int vl = t * 8 + wv;              // node slot; uniform across wave
        const int v  = bb * 64 + vl;
        if (v >= N) continue;                   // wave-uniform branch

        const float dv = dinv[v];
        float acc[8];
        if (g == 0) {                            // self-loop term ONCE per wave
            us8 h = *(const us8*)(hs + (size_t)v * D + sl * 8);
#pragma unroll
            for (int j = 0; j < 8; ++j) acc[j] = bf2f(h[j]) * dv;
        } else {
#pragma unroll
            for (int j = 0; j < 8; ++j) acc[j] = 0.f;
        }

        if (fits) {
            int i   = boff[vl] + g;
            int end = boff[vl] + bins[vl];
            for (; i + 4 < end; i += 8) {        // 2 edges per iter per group
                int s0 = srt[i];
                int s1 = srt[i + 4];
                float d0 = dinv[s0], d1 = dinv[s1];
                us8 m0 = *(const us8*)(hs + (size_t)s0 * D + sl * 8);
                us8 m1 = *(const us8*)(hs + (size_t)s1 * D + sl * 8);
#pragma unroll
                for (int j = 0; j < 8; ++j)
                    acc[j] += bf2f(m0[j]) * d0 + bf2f(m1[j]) * d1;
            }
            if (i < end) {
                int s = srt[i];
                float ds = dinv[s];
                us8 m = *(const us8*)(hs + (size_t)s * D + sl * 8);
#pragma unroll
                for (int j = 0; j < 8; ++j) acc[j] += bf2f(m[j]) * ds;
            }
        } else {
            // overflow fallback: group-strided filter-scan
            for (int i = g; i < cnt; i += 4) {
                unsigned int e = sorted[off + i];
                if ((int)((e >> 16) & 63u) == vl) {
                    int s = (int)(e & 0xFFFFu);
                    float ds = dinv[s];
                    us8 m = *(const us8*)(hs + (size_t)s * D + sl * 8);
#pragma unroll
                    for (int j = 0; j < 8; ++j) acc[j] += bf2f(m[j]) * ds;
                }
            }
        }

        // cross-group reduction (all 64 lanes active: shfl safe)
#pragma unroll
        for (int j = 0; j < 8; ++j) {
            acc[j] += __shfl_xor(acc[j], 16, 64);
            acc[j] += __shfl_xor(acc[j], 32, 64);
        }

        if (g == 0) {
            f32x4 o0, o1;
#pragma unroll
            for (int j = 0; j < 4; ++j) {
                o0[j] = fmaxf(fmaf(acc[j],     dv, b0[j]), 0.0f);
                o1[j] = fmaxf(fmaf(acc[4 + j], dv, b1[j]), 0.0f);
            }
            float* op = out + (size_t)v * D + sl * 8;
            *(f32x4*)op       = o0;
            *(f32x4*)(op + 4) = o1;
        }
    }
}

// ---------------------------------------------------------------------------
static inline char* align_up(char* p, size_t a) {
    return (char*)(((uintptr_t)p + a - 1) & ~(uintptr_t)(a - 1));
}

extern "C" void kernel_launch(void* const* d_in, const int* in_sizes, int n_in,
                              void* d_out, int out_size, void* d_ws, size_t ws_size,
                              hipStream_t stream) {
    const float* x  = (const float*)d_in[0];   // [N, D]
    const float* W  = (const float*)d_in[1];   // [D, D]
    const float* b  = (const float*)d_in[2];   // [D]
    const int*   ei = (const int*)d_in[3];     // [2, E]

    const int N = in_sizes[0] / D;             // 50000 (must be <= 65536)
    const int E = in_sizes[3] / 2;             // 600000
    const int* src = ei;
    const int* dst = ei + E;

    const int nbuck = (N + 63) >> 6;           // 782 (must be <= 1024)

    // workspace: counts2d[nbuck*NBH] btot[nbuck] offsets[nbuck+1] (int) |
    // sorted[E] u32 | dinv[N] f32 | Wt[D*D] bf16 | hs[N*D] bf16.
    // No memsets needed: every word is fully written before it is read.
    char* p = (char*)d_ws;
    int* counts2d        = (int*)p;            p = align_up(p + sizeof(int) * nbuck * NBH, 64);
    int* btot            = (int*)p;            p = align_up(p + sizeof(int) * nbuck, 64);
    int* offsets         = (int*)p;            p = align_up(p + sizeof(int) * (nbuck + 1), 64);
    unsigned int* sorted = (unsigned int*)p;   p = align_up(p + sizeof(unsigned int) * E, 64);
    float* dinv          = (float*)p;          p = align_up(p + sizeof(float) * N, 64);
    unsigned short* Wt   = (unsigned short*)p; p = align_up(p + sizeof(short) * D * D, 64);
    unsigned short* hs   = (unsigned short*)p;

    float* out = (float*)d_out;

    const int gemm_blks = (N + 63) / 64;       // 782

    k_wprep<<<(D * D) / 256, 256, 0, stream>>>(W, Wt);
    k_gemm_hist<<<NBH + gemm_blks, 256, 0, stream>>>(x, Wt, dst, counts2d, hs, N, E, nbuck);
    k_colscan<<<nbuck, 256, 0, stream>>>(counts2d, btot);
    k_scatter<<<NBH, 256, 0, stream>>>(src, dst, btot, counts2d, offsets, sorted, E, nbuck);
    k_dinv<<<nbuck, 256, 0, stream>>>(sorted, offsets, dinv, N);
    k_aggregate<<<nbuck, 512, 0, stream>>>(hs, sorted, offsets, dinv, b, out, N);
}

// Round 27
// 82.558 us; speedup vs baseline: 1.0412x; 1.0412x over previous
//
#include <hip/hip_runtime.h>

#define D 128
#define NBH 256           // edge-pass blocks; hist and scatter MUST use identical chunking
#define CAP 4096          // max edges per bucket staged in LDS (safe fallback beyond)

typedef __attribute__((ext_vector_type(8))) short bf16x8;
typedef __attribute__((ext_vector_type(4))) float f32x4;
typedef __attribute__((ext_vector_type(8))) unsigned short us8;
typedef __attribute__((ext_vector_type(4))) int i32x4;

static __device__ __forceinline__ float bf2f(unsigned short u) {
    union { unsigned int i; float f; } c; c.i = ((unsigned int)u) << 16; return c.f;
}
static __device__ __forceinline__ unsigned short f2bf(float f) {
    union { float f; unsigned int i; } c; c.f = f;
    unsigned int r = c.i + 0x7FFFu + ((c.i >> 16) & 1u);   // RTN-even
    return (unsigned short)(r >> 16);
}

// ---------------------------------------------------------------------------
// Wt[c][k] = bf16(W[k][c])  (one-time 32 KB transpose+convert; L2-resident)
__global__ __launch_bounds__(256) void k_wprep(const float* __restrict__ W,
                                               unsigned short* __restrict__ Wt) {
    int t = (int)blockIdx.x * 256 + (int)threadIdx.x;
    int k = t >> 7, c = t & 127;
    Wt[c * D + k] = f2bf(W[t]);
}

// ---------------------------------------------------------------------------
// Fused (R18-proven pairing): blocks [0, NBH) = bucket histogram (LDS bins ->
// bucket-major counts2d, zero global atomics) — hides under the GEMM;
// blocks [NBH, ...) = MFMA GEMM hs = bf16(x@W) (unscaled).
__global__ __launch_bounds__(256) void k_gemm_hist(const float* __restrict__ x,
                                                   const unsigned short* __restrict__ Wt,
                                                   const int* __restrict__ dst,
                                                   int* __restrict__ counts2d,
                                                   unsigned short* __restrict__ hs,
                                                   int N, int E, int nbuck) {
    if ((int)blockIdx.x < NBH) {
        __shared__ int bins[1024];                 // nbuck <= 1024
        for (int t = threadIdx.x; t < nbuck; t += 256) bins[t] = 0;
        __syncthreads();
        const int k = (int)blockIdx.x;
        const long long stride = (long long)NBH * 1024;   // NBH*256*4
        for (long long i = ((long long)k * 256 + threadIdx.x) * 4; i < E; i += stride) {
            if (i + 4 <= E) {
                i32x4 d = *(const i32x4*)(dst + i);
                atomicAdd(&bins[d.x >> 6], 1);
                atomicAdd(&bins[d.y >> 6], 1);
                atomicAdd(&bins[d.z >> 6], 1);
                atomicAdd(&bins[d.w >> 6], 1);
            } else {
                for (long long j = i; j < E; ++j) atomicAdd(&bins[dst[j] >> 6], 1);
            }
        }
        __syncthreads();
        for (int t = threadIdx.x; t < nbuck; t += 256)
            counts2d[t * NBH + k] = bins[t];       // bucket-major
        return;
    }

    // ---- GEMM role: 64 rows per block, 16 per wave (proven body) ----
    const int wave = threadIdx.x >> 6;
    const int l    = threadIdx.x & 63;
    const int m0   = ((int)blockIdx.x - NBH) * 64 + wave * 16;
    const int lr   = l & 15;
    const int kg   = l >> 4;
    const int row_a = m0 + lr;

    f32x4 acc[8];
#pragma unroll
    for (int t = 0; t < 8; ++t) acc[t] = (f32x4){0.f, 0.f, 0.f, 0.f};

#pragma unroll
    for (int kk = 0; kk < 4; ++kk) {
        const int kbase = kk * 32 + kg * 8;
        bf16x8 afrag;
        if (row_a < N) {
            const float* xp = x + (size_t)row_a * D + kbase;
            f32x4 x0 = *(const f32x4*)xp;
            f32x4 x1 = *(const f32x4*)(xp + 4);
#pragma unroll
            for (int j = 0; j < 4; ++j) afrag[j] = (short)f2bf(x0[j]);
#pragma unroll
            for (int j = 0; j < 4; ++j) afrag[4 + j] = (short)f2bf(x1[j]);
        } else {
#pragma unroll
            for (int j = 0; j < 8; ++j) afrag[j] = 0;
        }
#pragma unroll
        for (int nt = 0; nt < 8; ++nt) {
            bf16x8 bfrag = *(const bf16x8*)(Wt + (size_t)(nt * 16 + lr) * D + kbase);
            acc[nt] = __builtin_amdgcn_mfma_f32_16x16x32_bf16(afrag, bfrag, acc[nt], 0, 0, 0);
        }
    }

    // D-frag: col = lane&15, row = 4*(lane>>4)+j  (m89-verified)
#pragma unroll
    for (int j = 0; j < 4; ++j) {
        int row = m0 + kg * 4 + j;
        if (row < N) {
#pragma unroll
            for (int nt = 0; nt < 8; ++nt)
                hs[(size_t)row * D + nt * 16 + lr] = f2bf(acc[nt][j]);
        }
    }
}

// ---------------------------------------------------------------------------
// Per-bucket column scan: block b coalesced-loads its 256 per-block counts,
// LDS-scans them, writes back exclusive prefixes (colpre), emits btot[b].
__global__ __launch_bounds__(256) void k_colscan(int* __restrict__ counts2d,
                                                 int* __restrict__ btot) {
    __shared__ int ts[256];
    const int b = (int)blockIdx.x;
    const int t = (int)threadIdx.x;
    int c = counts2d[b * NBH + t];
    ts[t] = c;
    __syncthreads();
    for (int off = 1; off < 256; off <<= 1) {
        int v = (t >= off) ? ts[t - off] : 0;
        __syncthreads();
        ts[t] += v;
        __syncthreads();
    }
    counts2d[b * NBH + t] = ts[t] - c;             // exclusive colpre
    if (t == 255) btot[b] = ts[255];
}

// ---------------------------------------------------------------------------
// Deterministic scatter + inline bucket-offset scan (btscan folded in):
// every block independently computes the exclusive prefix of btot[0..nbuck)
// in LDS, publishes the identical offsets[] values (duplicate-store-safe),
// then scatters its edge subset: position = pref[b] + colpre[b][k] + cursor.
// Zero global atomics. Packed entry: src(16b) | (dst&63)<<16.  N <= 65536.
__global__ __launch_bounds__(256) void k_scatter(const int* __restrict__ src,
                                                 const int* __restrict__ dst,
                                                 const int* __restrict__ btot,
                                                 const int* __restrict__ counts2d,
                                                 int* __restrict__ offsets,
                                                 unsigned int* __restrict__ sorted,
                                                 int E, int nbuck) {
    __shared__ int pref[1025];     // exclusive prefix of btot; pref[nbuck] = total
    __shared__ int ts[256];
    __shared__ int base_l[1024];
    __shared__ int cur[1024];

    // ---- inline exclusive scan of btot (all 256 threads, 4 elems each) ----
    {
        const int t = (int)threadIdx.x;
        int e[4];
        int s = 0;
#pragma unroll
        for (int j = 0; j < 4; ++j) {
            int idx = t * 4 + j;
            int v = (idx < nbuck) ? btot[idx] : 0;
            e[j] = s;
            s += v;
        }
        ts[t] = s;
        __syncthreads();
        for (int off = 1; off < 256; off <<= 1) {
            int v = (t >= off) ? ts[t - off] : 0;
            __syncthreads();
            ts[t] += v;
            __syncthreads();
        }
        int base = ts[t] - s;
#pragma unroll
        for (int j = 0; j < 4; ++j) {
            int idx = t * 4 + j;
            pref[idx] = base + e[j];
        }
        if (t == 255) pref[1024] = ts[255];
        __syncthreads();
        // publish offsets[0..nbuck] (identical values from every block)
        for (int idx = t; idx <= nbuck; idx += 256)
            offsets[idx] = pref[idx];
    }

    const int k = (int)blockIdx.x;
    for (int t = threadIdx.x; t < nbuck; t += 256) {
        base_l[t] = pref[t] + counts2d[t * NBH + k];
        cur[t] = 0;
    }
    __syncthreads();

    const long long stride = (long long)NBH * 1024;
    for (long long i = ((long long)k * 256 + threadIdx.x) * 4; i < E; i += stride) {
        if (i + 4 <= E) {
            i32x4 d = *(const i32x4*)(dst + i);
            i32x4 s = *(const i32x4*)(src + i);
            int p;
            p = base_l[d.x >> 6] + atomicAdd(&cur[d.x >> 6], 1);
            sorted[p] = (unsigned int)(s.x & 0xFFFF) | ((unsigned int)(d.x & 63) << 16);
            p = base_l[d.y >> 6] + atomicAdd(&cur[d.y >> 6], 1);
            sorted[p] = (unsigned int)(s.y & 0xFFFF) | ((unsigned int)(d.y & 63) << 16);
            p = base_l[d.z >> 6] + atomicAdd(&cur[d.z >> 6], 1);
            sorted[p] = (unsigned int)(s.z & 0xFFFF) | ((unsigned int)(d.z & 63) << 16);
            p = base_l[d.w >> 6] + atomicAdd(&cur[d.w >> 6], 1);
            sorted[p] = (unsigned int)(s.w & 0xFFFF) | ((unsigned int)(d.w & 63) << 16);
        } else {
            for (long long j = i; j < E; ++j) {
                int dd = dst[j], ss = src[j];
                int p = base_l[dd >> 6] + atomicAdd(&cur[dd >> 6], 1);
                sorted[p] = (unsigned int)(ss & 0xFFFF) | ((unsigned int)(dd & 63) << 16);
            }
        }
    }
}

// ---------------------------------------------------------------------------
// Per-bucket node degrees -> dinv (reads the bucket's packed edges once).
__global__ __launch_bounds__(256) void k_dinv(const unsigned int* __restrict__ sorted,
                                              const int* __restrict__ offsets,
                                              float* __restrict__ dinv, int N) {
    __shared__ int bins[64];
    const int b = (int)blockIdx.x;
    if (threadIdx.x < 64) bins[threadIdx.x] = 0;
    __syncthreads();
    const int off = offsets[b];
    const int cnt = offsets[b + 1] - off;
    for (int i = threadIdx.x; i < cnt; i += 256)
        atomicAdd(&bins[(sorted[off + i] >> 16) & 63], 1);
    __syncthreads();
    if (threadIdx.x < 64) {
        int v = b * 64 + (int)threadIdx.x;
        if (v < N) dinv[v] = rsqrtf((float)(bins[threadIdx.x] + 1));
    }
}

// ---------------------------------------------------------------------------
// HALF-bucket aggregate (R23/R25-proven best): grid = nbuck*2; block
// (bb, half) owns the 32 nodes [half*32, half*32+32) of bucket bb.
// Counting-sort of the half's edges into a mini-CSR, then 32 groups x 16
// lanes, one gather pass:
//   acc = h[v]*dinv[v] + sum h[src]*dinv[src];  out[v] = relu(acc*dinv[v]+b)
__global__ __launch_bounds__(512) void k_aggregate(const unsigned short* __restrict__ hs,
                                                   const unsigned int* __restrict__ sorted,
                                                   const int* __restrict__ offsets,
                                                   const float* __restrict__ dinv,
                                                   const float* __restrict__ bias,
                                                   float* __restrict__ out, int N) {
    __shared__ unsigned short srt[CAP];
    __shared__ int bins[64];
    __shared__ int boff[64];
    __shared__ int cur[64];

    const int bb   = (int)blockIdx.x >> 1;
    const int half = (int)blockIdx.x & 1;
    const int off  = offsets[bb];
    const int cnt  = offsets[bb + 1] - off;
    const bool fits = (cnt <= CAP);

    if (fits) {
        if (threadIdx.x < 64) bins[threadIdx.x] = 0;
        __syncthreads();
        for (int i = threadIdx.x; i < cnt; i += 512) {
            int dl = (int)((sorted[off + i] >> 16) & 63u);
            if ((dl >> 5) == half) atomicAdd(&bins[dl], 1);
        }
        __syncthreads();
        if (threadIdx.x < 64) {              // full wave 0 active: shfl safe
            const int lane = (int)threadIdx.x;
            int bv = bins[lane];
            int inc = bv;
            for (int o = 1; o < 64; o <<= 1) {
                int t = __shfl_up(inc, o, 64);
                if (lane >= o) inc += t;
            }
            boff[lane] = inc - bv;
            cur[lane] = 0;
        }
        __syncthreads();
        for (int i = threadIdx.x; i < cnt; i += 512) {
            unsigned int e = sorted[off + i];
            int dl = (int)((e >> 16) & 63u);
            if ((dl >> 5) == half) {
                int p = boff[dl] + atomicAdd(&cur[dl], 1);
                srt[p] = (unsigned short)(e & 0xFFFFu);
            }
        }
        __syncthreads();
    }

    const int grp  = (int)(threadIdx.x >> 4);   // 0..31
    const int lane = (int)(threadIdx.x & 15);
    const f32x4 b0 = *(const f32x4*)(bias + lane * 8);
    const f32x4 b1 = *(const f32x4*)(bias + lane * 8 + 4);

    const int vl = half * 32 + grp;             // node slot within bucket
    const int v  = bb * 64 + vl;
    if (v >= N) return;

    const float dv = dinv[v];
    float acc[8];
    {
        us8 h = *(const us8*)(hs + (size_t)v * D + lane * 8);
#pragma unroll
        for (int j = 0; j < 8; ++j) acc[j] = bf2f(h[j]) * dv;   // self-loop
    }

    if (fits) {
        int i   = boff[vl];
        int end = i + bins[vl];
        for (; i + 4 <= end; i += 4) {
            int s0 = srt[i + 0];
            int s1 = srt[i + 1];
            int s2 = srt[i + 2];
            int s3 = srt[i + 3];
            float d0 = dinv[s0], d1 = dinv[s1], d2 = dinv[s2], d3 = dinv[s3];
            us8 m0 = *(const us8*)(hs + (size_t)s0 * D + lane * 8);
            us8 m1 = *(const us8*)(hs + (size_t)s1 * D + lane * 8);
            us8 m2 = *(const us8*)(hs + (size_t)s2 * D + lane * 8);
            us8 m3 = *(const us8*)(hs + (size_t)s3 * D + lane * 8);
#pragma unroll
            for (int j = 0; j < 8; ++j)
                acc[j] += (bf2f(m0[j]) * d0 + bf2f(m1[j]) * d1)
                        + (bf2f(m2[j]) * d2 + bf2f(m3[j]) * d3);
        }
        for (; i < end; ++i) {
            int s = srt[i];
            float ds = dinv[s];
            us8 m = *(const us8*)(hs + (size_t)s * D + lane * 8);
#pragma unroll
            for (int j = 0; j < 8; ++j) acc[j] += bf2f(m[j]) * ds;
        }
    } else {
        // overflow fallback: filter-scan (correct for any degree skew)
        for (int i = 0; i < cnt; ++i) {
            unsigned int e = sorted[off + i];
            if ((int)((e >> 16) & 63u) == vl) {
                int s = (int)(e & 0xFFFFu);
                float ds = dinv[s];
                us8 m = *(const us8*)(hs + (size_t)s * D + lane * 8);
#pragma unroll
                for (int j = 0; j < 8; ++j) acc[j] += bf2f(m[j]) * ds;
            }
        }
    }

    f32x4 o0, o1;
#pragma unroll
    for (int j = 0; j < 4; ++j) {
        o0[j] = fmaxf(fmaf(acc[j],     dv, b0[j]), 0.0f);
        o1[j] = fmaxf(fmaf(acc[4 + j], dv, b1[j]), 0.0f);
    }
    float* op = out + (size_t)v * D + lane * 8;
    *(f32x4*)op       = o0;
    *(f32x4*)(op + 4) = o1;
}

// ---------------------------------------------------------------------------
static inline char* align_up(char* p, size_t a) {
    return (char*)(((uintptr_t)p + a - 1) & ~(uintptr_t)(a - 1));
}

extern "C" void kernel_launch(void* const* d_in, const int* in_sizes, int n_in,
                              void* d_out, int out_size, void* d_ws, size_t ws_size,
                              hipStream_t stream) {
    const float* x  = (const float*)d_in[0];   // [N, D]
    const float* W  = (const float*)d_in[1];   // [D, D]
    const float* b  = (const float*)d_in[2];   // [D]
    const int*   ei = (const int*)d_in[3];     // [2, E]

    const int N = in_sizes[0] / D;             // 50000 (must be <= 65536)
    const int E = in_sizes[3] / 2;             // 600000
    const int* src = ei;
    const int* dst = ei + E;

    const int nbuck = (N + 63) >> 6;           // 782 (must be <= 1024)

    // workspace: counts2d[nbuck*NBH] btot[nbuck] offsets[nbuck+1] (int) |
    // sorted[E] u32 | dinv[N] f32 | Wt[D*D] bf16 | hs[N*D] bf16.
    // No memsets needed: every word is fully written before it is read.
    char* p = (char*)d_ws;
    int* counts2d        = (int*)p;            p = align_up(p + sizeof(int) * nbuck * NBH, 64);
    int* btot            = (int*)p;            p = align_up(p + sizeof(int) * nbuck, 64);
    int* offsets         = (int*)p;            p = align_up(p + sizeof(int) * (nbuck + 1), 64);
    unsigned int* sorted = (unsigned int*)p;   p = align_up(p + sizeof(unsigned int) * E, 64);
    float* dinv          = (float*)p;          p = align_up(p + sizeof(float) * N, 64);
    unsigned short* Wt   = (unsigned short*)p; p = align_up(p + sizeof(short) * D * D, 64);
    unsigned short* hs   = (unsigned short*)p;

    float* out = (float*)d_out;

    const int gemm_blks = (N + 63) / 64;       // 782

    k_wprep<<<(D * D) / 256, 256, 0, stream>>>(W, Wt);
    k_gemm_hist<<<NBH + gemm_blks, 256, 0, stream>>>(x, Wt, dst, counts2d, hs, N, E, nbuck);
    k_colscan<<<nbuck, 256, 0, stream>>>(counts2d, btot);
    k_scatter<<<NBH, 256, 0, stream>>>(src, dst, btot, counts2d, offsets, sorted, E, nbuck);
    k_dinv<<<nbuck, 256, 0, stream>>>(sorted, offsets, dinv, N);
    k_aggregate<<<nbuck * 2, 512, 0, stream>>>(hs, sorted, offsets, dinv, b, out, N);
}